// Round 6
// baseline (341.052 us; speedup 1.0000x reference)
//
#include <hip/hip_runtime.h>
#include <hip/hip_bf16.h>
#include <math.h>

#define NB   16
#define C1   256
#define C2   256
#define NK   5
#define NEXP (C2 * NK)   // 1280
#define HW   4096

typedef __attribute__((ext_vector_type(8))) short bf16x8;
typedef __attribute__((ext_vector_type(4))) float f32x4;

#define GLOAD_LDS16(g, l) __builtin_amdgcn_global_load_lds( \
    (const __attribute__((address_space(1))) void*)(g), \
    (__attribute__((address_space(3))) void*)(l), 16, 0, 0)

// 16B-chunk swizzle key for LDS row r (4 chunks per 64B row)
__device__ __forceinline__ int swzkey(int r) { return ((r >> 1) & 3) ^ ((r >> 3) & 3); }

__device__ __forceinline__ unsigned short bfbits(float v) {
    return __builtin_bit_cast(unsigned short, __float2bfloat16(v));
}

// ---------------------------------------------------------------------------
__global__ void weff_kernel(const float* __restrict__ w_path, float* __restrict__ weff) {
    int idx = blockIdx.x * 256 + threadIdx.x;
    if (idx >= NK * C2 * 9) return;
    float s = 0.f;
    #pragma unroll
    for (int p = 0; p < 3; ++p)
        s += w_path[(long)p * NK * C2 * 9 + idx];
    weff[idx] = s;
}

__global__ void cvt_bf16_kernel(const float* __restrict__ in, __hip_bfloat16* __restrict__ out, int n) {
    int i = blockIdx.x * 256 + threadIdx.x;
    if (i < n) out[i] = __float2bfloat16(in[i]);
}

// ---------------------------------------------------------------------------
// MFMA bf16 GEMM, 128x128 tile, BK=32, 4 waves, double-buffered LDS.
// A: bf16 [M][K], gload_lds with pre-swizzled source (conflict-free reads).
// B: [K][N] (fp32/bf16), reg-staged: 16 imm-offset scalar loads -> k-pair
//    pack -> 8 swizzled ds_write_b32 with SPREAD n = ng+16*jj (2-way = free).
// MFMA operands swapped (D'[n][m]) -> vectorized epilogue stores.
// ---------------------------------------------------------------------------
template <int NN, int KK, bool FP32B, bool OUT_BF16>
__global__ __launch_bounds__(256)
void gemm_mfma_kernel(const __hip_bfloat16* __restrict__ A,   // [M][KK]
                      const void* __restrict__ B_all,         // [z][KK][NN]
                      void* __restrict__ C_all, int M,
                      long bStrideB, long bStrideC, int bOffB, int bOffC,
                      const float* __restrict__ bn_gamma, const float* __restrict__ bn_beta,
                      const float* __restrict__ bn_mean, const float* __restrict__ bn_var) {
    __shared__ __align__(16) short As[2][128 * 32];
    __shared__ __align__(16) short Bs[2][128 * 32];
    const int z = blockIdx.z;
    const int m0 = blockIdx.x * 128;   // m fastest: consecutive blocks share B panel
    const int n0 = blockIdx.y * 128;
    const int t = threadIdx.x;
    const int lane = t & 63;
    const int wid = t >> 6;
    const int wr = wid >> 1, wc = wid & 1;
    const int lr = lane & 15, lg = lane >> 4;

    // ---- A staging: dest chunk (row=t>>2, chk=t&3) <- logical chunk chk^key
    const int arow = t >> 2, achk = t & 3;
    const int akey = swzkey(arow);           // same for arow and arow+64
    const __hip_bfloat16* aS0 = A + (long)(m0 + arow) * KK + (achk ^ akey) * 8;
    const __hip_bfloat16* aS1 = A + (long)(m0 + 64 + arow) * KK + (achk ^ akey) * 8;

    // ---- B staging ids: k-pair pr (k=2pr,2pr+1), n = ng + 16*jj (spread)
    const int pr = (t >> 4) & 15;
    const int ng = t & 15;
    const char* Bbase = (const char*)B_all + (long)(bOffB + z) * bStrideB * (FP32B ? 4 : 2);

    int bwoff[8];
    #pragma unroll
    for (int jj = 0; jj < 8; ++jj) {
        int n = ng + 16 * jj;
        bwoff[jj] = n * 64 + (((pr >> 2) ^ swzkey(n)) << 4) + (pr & 3) * 4;
    }
    int aroff[4], broff[4];
    #pragma unroll
    for (int i = 0; i < 4; ++i) {
        int r = wr * 64 + i * 16 + lr;
        aroff[i] = r * 64 + ((lg ^ swzkey(r)) << 4);
        int n = wc * 64 + i * 16 + lr;
        broff[i] = n * 64 + ((lg ^ swzkey(n)) << 4);
    }

    auto loadB = [&](int k0, unsigned u[8]) {
        if constexpr (FP32B) {
            const float* p = (const float*)Bbase + (long)(k0 + 2 * pr) * NN + n0 + ng;
            #pragma unroll
            for (int jj = 0; jj < 8; ++jj) {
                float v0 = p[jj * 16];
                float v1 = p[NN + jj * 16];
                u[jj] = (unsigned)bfbits(v0) | ((unsigned)bfbits(v1) << 16);
            }
        } else {
            const short* p = (const short*)Bbase + (long)(k0 + 2 * pr) * NN + n0 + ng;
            #pragma unroll
            for (int jj = 0; jj < 8; ++jj) {
                u[jj] = (unsigned)(unsigned short)p[jj * 16] |
                        ((unsigned)(unsigned short)p[NN + jj * 16] << 16);
            }
        }
    };

    f32x4 acc[4][4];
    #pragma unroll
    for (int i = 0; i < 4; ++i)
        #pragma unroll
        for (int j = 0; j < 4; ++j)
            acc[i][j] = (f32x4){0.f, 0.f, 0.f, 0.f};

    const int NT = KK / 32;
    // prologue: stage tile 0 into buf 0
    unsigned ub[8];
    loadB(0, ub);
    GLOAD_LDS16(aS0, (char*)&As[0][0] + t * 16);
    GLOAD_LDS16(aS1, (char*)&As[0][0] + 4096 + t * 16);
    #pragma unroll
    for (int jj = 0; jj < 8; ++jj)
        *(unsigned*)((char*)&Bs[0][0] + bwoff[jj]) = ub[jj];
    __syncthreads();

    int buf = 0;
    for (int it = 0; it < NT; ++it) {
        unsigned un[8];
        const bool more = (it + 1) < NT;
        if (more) {
            int k0 = (it + 1) * 32;
            loadB(k0, un);                               // issue-early
            GLOAD_LDS16(aS0 + k0, (char*)&As[buf ^ 1][0] + t * 16);
            GLOAD_LDS16(aS1 + k0, (char*)&As[buf ^ 1][0] + 4096 + t * 16);
        }
        bf16x8 af[4], bfr[4];
        #pragma unroll
        for (int i = 0; i < 4; ++i) {
            af[i]  = *(const bf16x8*)((const char*)&As[buf][0] + aroff[i]);
            bfr[i] = *(const bf16x8*)((const char*)&Bs[buf][0] + broff[i]);
        }
        #pragma unroll
        for (int i = 0; i < 4; ++i)
            #pragma unroll
            for (int j = 0; j < 4; ++j)
                acc[i][j] = __builtin_amdgcn_mfma_f32_16x16x32_bf16(bfr[j], af[i], acc[i][j], 0, 0, 0);
        if (more) {
            #pragma unroll
            for (int jj = 0; jj < 8; ++jj)
                *(unsigned*)((char*)&Bs[buf ^ 1][0] + bwoff[jj]) = un[jj];
        }
        __syncthreads();
        buf ^= 1;
    }

    // Epilogue: acc[i][j]: n = n0+wc*64+j*16+lg*4+r, m = m0+wr*64+i*16+lr
    if constexpr (OUT_BF16) {
        __hip_bfloat16* C = (__hip_bfloat16*)C_all + (long)(bOffC + z) * bStrideC;
        #pragma unroll
        for (int i = 0; i < 4; ++i) {
            const int m = m0 + wr * 64 + i * 16 + lr;
            #pragma unroll
            for (int j = 0; j < 4; ++j) {
                const long n = n0 + wc * 64 + j * 16 + lg * 4;
                short4 sv;
                sv.x = (short)bfbits(acc[i][j][0]);
                sv.y = (short)bfbits(acc[i][j][1]);
                sv.z = (short)bfbits(acc[i][j][2]);
                sv.w = (short)bfbits(acc[i][j][3]);
                *(short4*)(C + (long)m * NN + n) = sv;
            }
        }
    } else {
        float* C = (float*)C_all + (long)(bOffC + z) * bStrideC;
        #pragma unroll
        for (int i = 0; i < 4; ++i) {
            const int m = m0 + wr * 64 + i * 16 + lr;
            const float scale = bn_gamma[m] * rsqrtf(bn_var[m] + 1e-5f);
            const float mn = bn_mean[m], bt = bn_beta[m];
            #pragma unroll
            for (int j = 0; j < 4; ++j) {
                const long n = n0 + wc * 64 + j * 16 + lg * 4;
                float4 v;
                float t0 = (acc[i][j][0] - mn) * scale + bt;
                float t1 = (acc[i][j][1] - mn) * scale + bt;
                float t2 = (acc[i][j][2] - mn) * scale + bt;
                float t3 = (acc[i][j][3] - mn) * scale + bt;
                v.x = t0 / (1.0f + __expf(-t0));
                v.y = t1 / (1.0f + __expf(-t1));
                v.z = t2 / (1.0f + __expf(-t2));
                v.w = t3 / (1.0f + __expf(-t3));
                *(float4*)(C + (long)m * NN + n) = v;
            }
        }
    }
}

// ---------------------------------------------------------------------------
// Stage 2: roll + zero-padded depthwise 3x3 + sum over 5 shift groups.
// ---------------------------------------------------------------------------
__global__ __launch_bounds__(256)
void shift_dw_kernel(const __hip_bfloat16* __restrict__ xexp,  // [z][1280][4096]
                     const float* __restrict__ weff,           // [5][256][9]
                     __hip_bfloat16* __restrict__ merged) {    // [z][256][4096]
    __shared__ __align__(16) __hip_bfloat16 sd[NK * 34 * 64];  // 21760 B
    const int t  = threadIdx.x;
    const int r0 = blockIdx.x * 32;        // 0 or 32
    const int c  = blockIdx.y;
    const int z  = blockIdx.z;
    const int shifts[NK] = {-4, -1, 2, 5, 8};
    const __hip_bfloat16* base = xexp + ((long)z * NEXP + (long)c * NK) * HW;

    for (int idx = t; idx < NK * 34 * 8; idx += 256) {
        int k   = idx / (34 * 8);
        int rem = idx - k * (34 * 8);
        int rr  = rem >> 3, ch = (rem & 7) * 8;
        int grow = (r0 - 1 + rr - shifts[k]) & 63;
        *(bf16x8*)&sd[(k * 34 + rr) * 64 + ch] =
            *(const bf16x8*)(base + (long)k * HW + grow * 64 + ch);
    }
    __syncthreads();

    const int j  = t & 63;
    const int ty = t >> 6;                 // 0..3
    const int pbase = ty * 8;
    const bool topEdge = (r0 == 0)  && (ty == 0);
    const bool botEdge = (r0 == 32) && (ty == 3);

    float2 acc[4];
    #pragma unroll
    for (int i = 0; i < 4; ++i) acc[i] = (float2){0.f, 0.f};

    #pragma unroll
    for (int k = 0; k < NK; ++k) {
        const int s = shifts[k];
        const int cL = (j - 1 - s) & 63;
        const int cC = (j - s) & 63;
        const int cR = (j + 1 - s) & 63;
        const float* wp = &weff[((long)k * C2 + c) * 9];
        float w[9];
        #pragma unroll
        for (int i = 0; i < 9; ++i) w[i] = wp[i];
        if (j == 0)  { w[0] = 0.f; w[3] = 0.f; w[6] = 0.f; }
        if (j == 63) { w[2] = 0.f; w[5] = 0.f; w[8] = 0.f; }
        const __hip_bfloat16* pl = &sd[k * 34 * 64];

        float vL[4], vC[4], vR[4];
        #pragma unroll
        for (int w4 = 0; w4 < 4; ++w4) {
            vL[w4] = __bfloat162float(pl[(pbase + w4) * 64 + cL]);
            vC[w4] = __bfloat162float(pl[(pbase + w4) * 64 + cC]);
            vR[w4] = __bfloat162float(pl[(pbase + w4) * 64 + cR]);
        }
        if (topEdge) { vL[0] = 0.f; vC[0] = 0.f; vR[0] = 0.f; }

        #pragma unroll
        for (int pr = 0; pr < 4; ++pr) {
            #pragma unroll
            for (int u = 0; u < 3; ++u) {
                const int wi  = (2 * pr + u) & 3;
                const int wi2 = (2 * pr + u + 1) & 3;
                acc[pr].x += w[u*3+0] * vL[wi]  + w[u*3+1] * vC[wi]  + w[u*3+2] * vR[wi];
                acc[pr].y += w[u*3+0] * vL[wi2] + w[u*3+1] * vC[wi2] + w[u*3+2] * vR[wi2];
            }
            if (pr < 3) {
                const int na = (2 * pr) & 3, nb = (2 * pr + 1) & 3;
                const int ra = pbase + 2 * pr + 4, rb = pbase + 2 * pr + 5;
                vL[na] = __bfloat162float(pl[ra * 64 + cL]);
                vC[na] = __bfloat162float(pl[ra * 64 + cC]);
                vR[na] = __bfloat162float(pl[ra * 64 + cR]);
                vL[nb] = __bfloat162float(pl[rb * 64 + cL]);
                vC[nb] = __bfloat162float(pl[rb * 64 + cC]);
                vR[nb] = __bfloat162float(pl[rb * 64 + cR]);
                if (botEdge && pr == 2) { vL[nb] = 0.f; vC[nb] = 0.f; vR[nb] = 0.f; }
            }
        }
    }

    long outb = ((long)z * C2 + c) * HW + (long)(r0 + ty * 8) * 64 + j;
    #pragma unroll
    for (int pr = 0; pr < 4; ++pr) {
        merged[outb + (long)(2 * pr) * 64]     = __float2bfloat16(acc[pr].x);
        merged[outb + (long)(2 * pr + 1) * 64] = __float2bfloat16(acc[pr].y);
    }
}

// ---------------------------------------------------------------------------
extern "C" void kernel_launch(void* const* d_in, const int* in_sizes, int n_in,
                              void* d_out, int out_size, void* d_ws, size_t ws_size,
                              hipStream_t stream) {
    const float* x        = (const float*)d_in[0];
    const float* w_expand = (const float*)d_in[1];
    const float* w_path   = (const float*)d_in[2];
    const float* w_mix    = (const float*)d_in[3];
    const float* bn_gamma = (const float*)d_in[4];
    const float* bn_beta  = (const float*)d_in[5];
    const float* bn_mean  = (const float*)d_in[6];
    const float* bn_var   = (const float*)d_in[7];

    char* ws = (char*)d_ws;
    float* weff             = (float*)ws;
    __hip_bfloat16* wexp_bf = (__hip_bfloat16*)(ws + 65536);
    __hip_bfloat16* wmix_bf = (__hip_bfloat16*)(ws + 65536 + 655360);
    const size_t head = 1 << 20;

    const size_t xe_per = (size_t)NEXP * HW * 2;   // 10 MB
    const size_t mg_per = (size_t)C2 * HW * 2;     // 2 MB
    const size_t per_b = xe_per + mg_per;          // 12 MB

    int g = 1;
    if (ws_size > head + per_b) {
        size_t fit = (ws_size - head) / per_b;
        g = (int)(fit < NB ? fit : NB);
        if (g < 1) g = 1;
    }

    char* p = ws + head;
    __hip_bfloat16* xexp   = (__hip_bfloat16*)p; p += (size_t)g * xe_per;
    __hip_bfloat16* merged = (__hip_bfloat16*)p;

    weff_kernel<<<(NK * C2 * 9 + 255) / 256, 256, 0, stream>>>(w_path, weff);
    cvt_bf16_kernel<<<(NEXP * C1 + 255) / 256, 256, 0, stream>>>(w_expand, wexp_bf, NEXP * C1);
    cvt_bf16_kernel<<<(C2 * C2 + 255) / 256, 256, 0, stream>>>(w_mix, wmix_bf, C2 * C2);

    for (int b0 = 0; b0 < NB; b0 += g) {
        int gb = (NB - b0) < g ? (NB - b0) : g;
        // expand: A = wexp_bf [1280x256], B = x [z][256][4096] fp32 -> xexp bf16
        gemm_mfma_kernel<HW, C1, true, true><<<dim3(NEXP / 128, HW / 128, gb), 256, 0, stream>>>(
            wexp_bf, x, xexp, NEXP,
            (long)C1 * HW, (long)NEXP * HW, b0, 0,
            nullptr, nullptr, nullptr, nullptr);
        shift_dw_kernel<<<dim3(2, C2, gb), 256, 0, stream>>>(xexp, weff, merged);
        // mix: A = wmix_bf [256x256], B = merged [z][256][4096] bf16 -> d_out fp32
        gemm_mfma_kernel<HW, C2, false, false><<<dim3(C2 / 128, HW / 128, gb), 256, 0, stream>>>(
            wmix_bf, merged, d_out, C2,
            (long)C2 * HW, (long)C2 * HW, 0, b0,
            bn_gamma, bn_beta, bn_mean, bn_var);
    }
}

// Round 7
// 256.760 us; speedup vs baseline: 1.3283x; 1.3283x over previous
//
#include <hip/hip_runtime.h>
#include <hip/hip_bf16.h>
#include <math.h>

#define NB   16
#define C1   256
#define C2   256
#define NK   5
#define NEXP (C2 * NK)   // 1280
#define HW   4096

typedef __attribute__((ext_vector_type(8))) short bf16x8;
typedef __attribute__((ext_vector_type(4))) float f32x4;

#define GLOAD_LDS16(g, l) __builtin_amdgcn_global_load_lds( \
    (const __attribute__((address_space(1))) void*)(g), \
    (__attribute__((address_space(3))) void*)(l), 16, 0, 0)

__device__ __forceinline__ unsigned short bfbits(float v) {
    return __builtin_bit_cast(unsigned short, __float2bfloat16(v));
}

// ---------------------------------------------------------------------------
__global__ void weff_kernel(const float* __restrict__ w_path, float* __restrict__ weff) {
    int idx = blockIdx.x * 256 + threadIdx.x;
    if (idx >= NK * C2 * 9) return;
    float s = 0.f;
    #pragma unroll
    for (int p = 0; p < 3; ++p)
        s += w_path[(long)p * NK * C2 * 9 + idx];
    weff[idx] = s;
}

__global__ void cvt_bf16_kernel(const float* __restrict__ in, __hip_bfloat16* __restrict__ out, int n) {
    int i = blockIdx.x * 256 + threadIdx.x;
    if (i < n) out[i] = __float2bfloat16(in[i]);
}

// ---------------------------------------------------------------------------
// MFMA bf16 GEMM, 128x128 tile, BK=32, 4 waves, double-buffered LDS.
// Grid: n fastest (blockIdx.x), proven L2-friendly (R4 bench: FETCH 37MB).
// A: bf16 [M][K], linear global_load_lds (dest = t*16).
// B: [K][N] fp32/bf16, k-strided scalar loads (wave = 256B contiguous/instr)
//    -> pack -> ds_write_b128 with light ((n>>1)&3) chunk swizzle (2.6M confl).
// MFMA operands swapped (D'[n][m]) -> vectorized epilogue stores.
// ---------------------------------------------------------------------------
template <int NN, int KK, bool FP32B, bool OUT_BF16>
__global__ __launch_bounds__(256)
void gemm_mfma_kernel(const __hip_bfloat16* __restrict__ A,   // [M][KK]
                      const void* __restrict__ B_all,         // [z][KK][NN]
                      void* __restrict__ C_all, int M,
                      long bStrideB, long bStrideC, int bOffB, int bOffC,
                      const float* __restrict__ bn_gamma, const float* __restrict__ bn_beta,
                      const float* __restrict__ bn_mean, const float* __restrict__ bn_var) {
    __shared__ __align__(16) short As[2][128 * 32];
    __shared__ __align__(16) short Bs[2][128 * 32];
    const int z = blockIdx.z;
    const int n0 = blockIdx.x * 128;   // n fastest
    const int m0 = blockIdx.y * 128;
    const int t = threadIdx.x;
    const int lane = t & 63;
    const int wid = t >> 6;
    const int wr = wid >> 1, wc = wid & 1;
    const int lr = lane & 15, lg = lane >> 4;

    // ---- A staging (linear)
    const __hip_bfloat16* aS0 = A + (long)(m0 + (t >> 2)) * KK + (t & 3) * 8;
    const __hip_bfloat16* aS1 = aS0 + (long)64 * KK;

    // ---- B staging: column bn (0..127), k-group kg (0/1)
    const int bn = t & 127;
    const int kg = t >> 7;
    const char* Bbase = (const char*)B_all + (long)(bOffB + z) * bStrideB * (FP32B ? 4 : 2);
    const int bkey = ((bn >> 1) & 3) << 4;
    const int bW0 = bn * 64 + ((kg * 32) ^ bkey);
    const int bW1 = bn * 64 + ((kg * 32 + 16) ^ bkey);

    // ---- fragment read offsets
    int aroff[4], broff[4];
    #pragma unroll
    for (int i = 0; i < 4; ++i) {
        aroff[i] = (wr * 64 + i * 16 + lr) * 64 + lg * 16;
        int n = wc * 64 + i * 16 + lr;
        broff[i] = n * 64 + ((lg * 16) ^ (((n >> 1) & 3) << 4));
    }

    auto loadB = [&](int k0, bf16x8& u0, bf16x8& u1) {
        if constexpr (FP32B) {
            const float* p = (const float*)Bbase + (long)(k0 + kg * 16) * NN + n0 + bn;
            #pragma unroll
            for (int i = 0; i < 8; ++i) u0[i] = (short)bfbits(p[(long)i * NN]);
            #pragma unroll
            for (int i = 0; i < 8; ++i) u1[i] = (short)bfbits(p[(long)(8 + i) * NN]);
        } else {
            const short* p = (const short*)Bbase + (long)(k0 + kg * 16) * NN + n0 + bn;
            #pragma unroll
            for (int i = 0; i < 8; ++i) u0[i] = p[(long)i * NN];
            #pragma unroll
            for (int i = 0; i < 8; ++i) u1[i] = p[(long)(8 + i) * NN];
        }
    };

    f32x4 acc[4][4];
    #pragma unroll
    for (int i = 0; i < 4; ++i)
        #pragma unroll
        for (int j = 0; j < 4; ++j)
            acc[i][j] = (f32x4){0.f, 0.f, 0.f, 0.f};

    const int NT = KK / 32;
    // prologue: stage tile 0 into buf 0
    bf16x8 u0, u1;
    loadB(0, u0, u1);
    GLOAD_LDS16(aS0, (char*)&As[0][0] + t * 16);
    GLOAD_LDS16(aS1, (char*)&As[0][0] + 4096 + t * 16);
    *(bf16x8*)((char*)&Bs[0][0] + bW0) = u0;
    *(bf16x8*)((char*)&Bs[0][0] + bW1) = u1;
    __syncthreads();

    int buf = 0;
    for (int it = 0; it < NT; ++it) {
        bf16x8 n0v, n1v;
        const bool more = (it + 1) < NT;
        if (more) {
            const int k0 = (it + 1) * 32;
            loadB(k0, n0v, n1v);                             // issue-early
            GLOAD_LDS16(aS0 + k0, (char*)&As[buf ^ 1][0] + t * 16);
            GLOAD_LDS16(aS1 + k0, (char*)&As[buf ^ 1][0] + 4096 + t * 16);
        }
        bf16x8 af[4], bfr[4];
        #pragma unroll
        for (int i = 0; i < 4; ++i) {
            af[i]  = *(const bf16x8*)((const char*)&As[buf][0] + aroff[i]);
            bfr[i] = *(const bf16x8*)((const char*)&Bs[buf][0] + broff[i]);
        }
        #pragma unroll
        for (int i = 0; i < 4; ++i)
            #pragma unroll
            for (int j = 0; j < 4; ++j)
                acc[i][j] = __builtin_amdgcn_mfma_f32_16x16x32_bf16(bfr[j], af[i], acc[i][j], 0, 0, 0);
        if (more) {
            *(bf16x8*)((char*)&Bs[buf ^ 1][0] + bW0) = n0v;
            *(bf16x8*)((char*)&Bs[buf ^ 1][0] + bW1) = n1v;
        }
        __syncthreads();
        buf ^= 1;
    }

    // Epilogue (swapped): acc[i][j]: n = n0+wc*64+j*16+lg*4+r, m = m0+wr*64+i*16+lr
    if constexpr (OUT_BF16) {
        __hip_bfloat16* C = (__hip_bfloat16*)C_all + (long)(bOffC + z) * bStrideC;
        #pragma unroll
        for (int i = 0; i < 4; ++i) {
            const int m = m0 + wr * 64 + i * 16 + lr;
            #pragma unroll
            for (int j = 0; j < 4; ++j) {
                const long n = n0 + wc * 64 + j * 16 + lg * 4;
                short4 sv;
                sv.x = (short)bfbits(acc[i][j][0]);
                sv.y = (short)bfbits(acc[i][j][1]);
                sv.z = (short)bfbits(acc[i][j][2]);
                sv.w = (short)bfbits(acc[i][j][3]);
                *(short4*)(C + (long)m * NN + n) = sv;
            }
        }
    } else {
        float* C = (float*)C_all + (long)(bOffC + z) * bStrideC;
        #pragma unroll
        for (int i = 0; i < 4; ++i) {
            const int m = m0 + wr * 64 + i * 16 + lr;
            const float scale = bn_gamma[m] * rsqrtf(bn_var[m] + 1e-5f);
            const float mn = bn_mean[m], bt = bn_beta[m];
            #pragma unroll
            for (int j = 0; j < 4; ++j) {
                const long n = n0 + wc * 64 + j * 16 + lg * 4;
                float4 v;
                float t0 = (acc[i][j][0] - mn) * scale + bt;
                float t1 = (acc[i][j][1] - mn) * scale + bt;
                float t2 = (acc[i][j][2] - mn) * scale + bt;
                float t3 = (acc[i][j][3] - mn) * scale + bt;
                v.x = t0 / (1.0f + __expf(-t0));
                v.y = t1 / (1.0f + __expf(-t1));
                v.z = t2 / (1.0f + __expf(-t2));
                v.w = t3 / (1.0f + __expf(-t3));
                *(float4*)(C + (long)m * NN + n) = v;
            }
        }
    }
}

// ---------------------------------------------------------------------------
// Stage 2: roll + zero-padded depthwise 3x3 + sum over 5 shift groups.
// ---------------------------------------------------------------------------
__global__ __launch_bounds__(256)
void shift_dw_kernel(const __hip_bfloat16* __restrict__ xexp,  // [z][1280][4096]
                     const float* __restrict__ weff,           // [5][256][9]
                     __hip_bfloat16* __restrict__ merged) {    // [z][256][4096]
    __shared__ __align__(16) __hip_bfloat16 sd[NK * 34 * 64];  // 21760 B
    const int t  = threadIdx.x;
    const int r0 = blockIdx.x * 32;        // 0 or 32
    const int c  = blockIdx.y;
    const int z  = blockIdx.z;
    const int shifts[NK] = {-4, -1, 2, 5, 8};
    const __hip_bfloat16* base = xexp + ((long)z * NEXP + (long)c * NK) * HW;

    for (int idx = t; idx < NK * 34 * 8; idx += 256) {
        int k   = idx / (34 * 8);
        int rem = idx - k * (34 * 8);
        int rr  = rem >> 3, ch = (rem & 7) * 8;
        int grow = (r0 - 1 + rr - shifts[k]) & 63;
        *(bf16x8*)&sd[(k * 34 + rr) * 64 + ch] =
            *(const bf16x8*)(base + (long)k * HW + grow * 64 + ch);
    }
    __syncthreads();

    const int j  = t & 63;
    const int ty = t >> 6;                 // 0..3
    const int pbase = ty * 8;
    const bool topEdge = (r0 == 0)  && (ty == 0);
    const bool botEdge = (r0 == 32) && (ty == 3);

    float2 acc[4];
    #pragma unroll
    for (int i = 0; i < 4; ++i) acc[i] = (float2){0.f, 0.f};

    #pragma unroll
    for (int k = 0; k < NK; ++k) {
        const int s = shifts[k];
        const int cL = (j - 1 - s) & 63;
        const int cC = (j - s) & 63;
        const int cR = (j + 1 - s) & 63;
        const float* wp = &weff[((long)k * C2 + c) * 9];
        float w[9];
        #pragma unroll
        for (int i = 0; i < 9; ++i) w[i] = wp[i];
        if (j == 0)  { w[0] = 0.f; w[3] = 0.f; w[6] = 0.f; }
        if (j == 63) { w[2] = 0.f; w[5] = 0.f; w[8] = 0.f; }
        const __hip_bfloat16* pl = &sd[k * 34 * 64];

        float vL[4], vC[4], vR[4];
        #pragma unroll
        for (int w4 = 0; w4 < 4; ++w4) {
            vL[w4] = __bfloat162float(pl[(pbase + w4) * 64 + cL]);
            vC[w4] = __bfloat162float(pl[(pbase + w4) * 64 + cC]);
            vR[w4] = __bfloat162float(pl[(pbase + w4) * 64 + cR]);
        }
        if (topEdge) { vL[0] = 0.f; vC[0] = 0.f; vR[0] = 0.f; }

        #pragma unroll
        for (int pr = 0; pr < 4; ++pr) {
            #pragma unroll
            for (int u = 0; u < 3; ++u) {
                const int wi  = (2 * pr + u) & 3;
                const int wi2 = (2 * pr + u + 1) & 3;
                acc[pr].x += w[u*3+0] * vL[wi]  + w[u*3+1] * vC[wi]  + w[u*3+2] * vR[wi];
                acc[pr].y += w[u*3+0] * vL[wi2] + w[u*3+1] * vC[wi2] + w[u*3+2] * vR[wi2];
            }
            if (pr < 3) {
                const int na = (2 * pr) & 3, nb = (2 * pr + 1) & 3;
                const int ra = pbase + 2 * pr + 4, rb = pbase + 2 * pr + 5;
                vL[na] = __bfloat162float(pl[ra * 64 + cL]);
                vC[na] = __bfloat162float(pl[ra * 64 + cC]);
                vR[na] = __bfloat162float(pl[ra * 64 + cR]);
                vL[nb] = __bfloat162float(pl[rb * 64 + cL]);
                vC[nb] = __bfloat162float(pl[rb * 64 + cC]);
                vR[nb] = __bfloat162float(pl[rb * 64 + cR]);
                if (botEdge && pr == 2) { vL[nb] = 0.f; vC[nb] = 0.f; vR[nb] = 0.f; }
            }
        }
    }

    long outb = ((long)z * C2 + c) * HW + (long)(r0 + ty * 8) * 64 + j;
    #pragma unroll
    for (int pr = 0; pr < 4; ++pr) {
        merged[outb + (long)(2 * pr) * 64]     = __float2bfloat16(acc[pr].x);
        merged[outb + (long)(2 * pr + 1) * 64] = __float2bfloat16(acc[pr].y);
    }
}

// ---------------------------------------------------------------------------
extern "C" void kernel_launch(void* const* d_in, const int* in_sizes, int n_in,
                              void* d_out, int out_size, void* d_ws, size_t ws_size,
                              hipStream_t stream) {
    const float* x        = (const float*)d_in[0];
    const float* w_expand = (const float*)d_in[1];
    const float* w_path   = (const float*)d_in[2];
    const float* w_mix    = (const float*)d_in[3];
    const float* bn_gamma = (const float*)d_in[4];
    const float* bn_beta  = (const float*)d_in[5];
    const float* bn_mean  = (const float*)d_in[6];
    const float* bn_var   = (const float*)d_in[7];

    char* ws = (char*)d_ws;
    float* weff             = (float*)ws;
    __hip_bfloat16* wexp_bf = (__hip_bfloat16*)(ws + 65536);
    __hip_bfloat16* wmix_bf = (__hip_bfloat16*)(ws + 65536 + 655360);
    const size_t head = 1 << 20;

    const size_t xe_per = (size_t)NEXP * HW * 2;   // 10 MB
    const size_t mg_per = (size_t)C2 * HW * 2;     // 2 MB
    const size_t per_b = xe_per + mg_per;          // 12 MB

    int g = 1;
    if (ws_size > head + per_b) {
        size_t fit = (ws_size - head) / per_b;
        g = (int)(fit < NB ? fit : NB);
        if (g < 1) g = 1;
    }

    char* p = ws + head;
    __hip_bfloat16* xexp   = (__hip_bfloat16*)p; p += (size_t)g * xe_per;
    __hip_bfloat16* merged = (__hip_bfloat16*)p;

    weff_kernel<<<(NK * C2 * 9 + 255) / 256, 256, 0, stream>>>(w_path, weff);
    cvt_bf16_kernel<<<(NEXP * C1 + 255) / 256, 256, 0, stream>>>(w_expand, wexp_bf, NEXP * C1);
    cvt_bf16_kernel<<<(C2 * C2 + 255) / 256, 256, 0, stream>>>(w_mix, wmix_bf, C2 * C2);

    for (int b0 = 0; b0 < NB; b0 += g) {
        int gb = (NB - b0) < g ? (NB - b0) : g;
        // expand: A = wexp_bf [1280x256], B = x [z][256][4096] fp32 -> xexp bf16
        gemm_mfma_kernel<HW, C1, true, true><<<dim3(HW / 128, NEXP / 128, gb), 256, 0, stream>>>(
            wexp_bf, x, xexp, NEXP,
            (long)C1 * HW, (long)NEXP * HW, b0, 0,
            nullptr, nullptr, nullptr, nullptr);
        shift_dw_kernel<<<dim3(2, C2, gb), 256, 0, stream>>>(xexp, weff, merged);
        // mix: A = wmix_bf [256x256], B = merged [z][256][4096] bf16 -> d_out fp32
        gemm_mfma_kernel<HW, C2, false, false><<<dim3(HW / 128, C2 / 128, gb), 256, 0, stream>>>(
            wmix_bf, merged, d_out, C2,
            (long)C2 * HW, (long)C2 * HW, 0, b0,
            bn_gamma, bn_beta, bn_mean, bn_var);
    }
}